// Round 5
// baseline (479.361 us; speedup 1.0000x reference)
//
#include <hip/hip_runtime.h>
#include <math.h>

#define B_  4
#define L_  1024
#define DM  1024
#define DI  1024
#define DS  16
#define DR  64
#define DCV 4
#define NH  4
#define DK  256

#define NCH 32         // scan time-chunks
#define CHL (L_ / NCH) // 32 steps per chunk

typedef __attribute__((ext_vector_type(8))) short short8;
typedef __attribute__((ext_vector_type(4))) float floatx4;

static __device__ __forceinline__ unsigned short f2bf(float f) {
    unsigned int u = __float_as_uint(f);
    u += 0x7fffu + ((u >> 16) & 1u);
    return (unsigned short)(u >> 16);
}
static __device__ __forceinline__ float bf2f(unsigned short s) {
    return __uint_as_float(((unsigned int)s) << 16);
}

// ---------------------------------------------------------------------------
// Fused fp32->bf16 casts (8 regions, grid.y selects; pads with zeros past ns)
// ---------------------------------------------------------------------------
struct CastArgs {
    const float* s[8];
    unsigned short* d[8];
    int n[8];
    int ns[8];
};

__global__ __launch_bounds__(256) void cast_multi(CastArgs ca)
{
    int y = blockIdx.y;
    int i = (blockIdx.x * 256 + threadIdx.x) * 4;
    if (i >= ca.n[y]) return;
    const float* s = ca.s[y];
    unsigned short* d = ca.d[y];
    int ns = ca.ns[y];
    ushort4 o;
    if (i + 4 <= ns) {
        float4 v = *(const float4*)(s + i);
        o.x = f2bf(v.x); o.y = f2bf(v.y); o.z = f2bf(v.z); o.w = f2bf(v.w);
    } else {
        float v[4];
#pragma unroll
        for (int j = 0; j < 4; j++) v[j] = (i + j < ns) ? s[i + j] : 0.f;
        o.x = f2bf(v[0]); o.y = f2bf(v[1]); o.z = f2bf(v[2]); o.w = f2bf(v[3]);
    }
    *(ushort4*)(d + i) = o;
}

// ---------------------------------------------------------------------------
// Multi-descriptor bf16 MFMA GEMM: per z, C = act(A @ W^T * scale + bias)
// mode & 3: 0 = fp32 out, 1 = bf16 out, 2 = both. mode & 4: softplus.
// ---------------------------------------------------------------------------
struct GDesc {
    const unsigned short* A;
    const unsigned short* W;
    const float* bias;
    float* Cf;
    unsigned short* Cb;
    int K, lda, ldw, ldc, ldc2;
    int mode;
    float scale;
    int gx, gy;
};
struct GArgs { GDesc g[3]; };

__global__ __launch_bounds__(256) void gemm_multi(GArgs ga)
{
    GDesc g = ga.g[blockIdx.z];
    if ((int)blockIdx.x >= g.gx || (int)blockIdx.y >= g.gy) return;

    __shared__ __align__(16) unsigned short Asm[128 * 32];
    __shared__ __align__(16) unsigned short Bsm[128 * 32];

    int tid = threadIdx.x;
    int wid = tid >> 6;
    int lane = tid & 63;
    int wm = wid & 1, wn = wid >> 1;
    int lr = lane & 15, quad = lane >> 4;

    const unsigned short* Ab = g.A + (size_t)blockIdx.y * 128 * g.lda;
    const unsigned short* Wb = g.W + (size_t)blockIdx.x * 128 * g.ldw;

    int srow = tid >> 2;
    int scol = (tid & 3) * 8;
    const unsigned short* Ap = Ab + (size_t)srow * g.lda + scol;
    const unsigned short* Wp = Wb + (size_t)srow * g.ldw + scol;

    unsigned short* lA0 = &Asm[(wid * 16) * 32];
    unsigned short* lA1 = &Asm[(64 + wid * 16) * 32];
    unsigned short* lB0 = &Bsm[(wid * 16) * 32];
    unsigned short* lB1 = &Bsm[(64 + wid * 16) * 32];

    floatx4 acc[4][4];
#pragma unroll
    for (int i = 0; i < 4; i++)
#pragma unroll
        for (int j = 0; j < 4; j++) acc[i][j] = (floatx4){0.f, 0.f, 0.f, 0.f};

#define GLL(gp, lp) __builtin_amdgcn_global_load_lds( \
        (const __attribute__((address_space(1))) void*)(gp), \
        (__attribute__((address_space(3))) void*)(lp), 16, 0, 0)

    for (int k0 = 0; k0 < g.K; k0 += 32) {
        GLL(Ap, lA0);
        GLL(Ap + (size_t)64 * g.lda, lA1);
        GLL(Wp, lB0);
        GLL(Wp + (size_t)64 * g.ldw, lB1);
        Ap += 32; Wp += 32;
        __syncthreads();

        short8 af[4], bf[4];
#pragma unroll
        for (int mt = 0; mt < 4; mt++)
            af[mt] = *(const short8*)&Asm[(wm * 64 + mt * 16 + lr) * 32 + quad * 8];
#pragma unroll
        for (int nt = 0; nt < 4; nt++)
            bf[nt] = *(const short8*)&Bsm[(wn * 64 + nt * 16 + lr) * 32 + quad * 8];
#pragma unroll
        for (int mt = 0; mt < 4; mt++)
#pragma unroll
            for (int nt = 0; nt < 4; nt++)
                acc[mt][nt] = __builtin_amdgcn_mfma_f32_16x16x32_bf16(
                    af[mt], bf[nt], acc[mt][nt], 0, 0, 0);
        __syncthreads();
    }
#undef GLL

    int bm = blockIdx.y * 128, bn = blockIdx.x * 128;
    int m = g.mode & 3;
#pragma unroll
    for (int mt = 0; mt < 4; mt++) {
#pragma unroll
        for (int nt = 0; nt < 4; nt++) {
            int row0 = bm + wm * 64 + mt * 16 + quad * 4;
            int col = bn + wn * 64 + nt * 16 + lr;
            float bv = g.bias ? g.bias[col] : 0.f;
#pragma unroll
            for (int i = 0; i < 4; i++) {
                float v = acc[mt][nt][i] * g.scale + bv;
                if (g.mode & 4) v = (v > 15.f) ? v : log1pf(__expf(v));
                if (m == 0) {
                    g.Cf[(size_t)(row0 + i) * g.ldc + col] = v;
                } else if (m == 1) {
                    g.Cb[(size_t)(row0 + i) * g.ldc + col] = f2bf(v);
                } else {
                    g.Cf[(size_t)(row0 + i) * g.ldc + col] = v;
                    g.Cb[(size_t)(row0 + i) * g.ldc2 + col] = f2bf(v);
                }
            }
        }
    }
}

// ---------------------------------------------------------------------------
// Flash attention: grid (16 q-tiles, 16 bh), 256 thr = 4 waves x 16 q-rows.
// Q frags in registers (whole 256-dim), K-tile (64 keys) staged in LDS,
// V frags from pre-transposed VT (global/L2), P via per-wave LDS round-trip.
// Online softmax in fp32. Out: AO bf16 [4096][1024].
// ---------------------------------------------------------------------------
__global__ __launch_bounds__(256) void flash_attn(
    const unsigned short* __restrict__ Q, const unsigned short* __restrict__ Kg,
    const unsigned short* __restrict__ VT, unsigned short* __restrict__ O)
{
    __shared__ __align__(16) unsigned short Ks[64 * 264];   // 64 keys x 256 dims, pitch 264
    __shared__ __align__(16) unsigned short Pp[4 * 16 * 72]; // per-wave 16 rows x 64 keys, pitch 72

    int bh = blockIdx.y;
    int b = bh >> 2, h = bh & 3;
    int q0 = blockIdx.x * 64;
    int tid = threadIdx.x;
    int wid = tid >> 6, lane = tid & 63;
    int lr = lane & 15, quad = lane >> 4;
    const float scale = 0.0625f;   // 1/sqrt(256)

    // Q fragments: rows q0 + wid*16 + lr, all 256 dims (8 k-frags)
    short8 qf[8];
    const unsigned short* qbase = Q + ((size_t)(b * L_ + q0 + wid * 16 + lr)) * 1024 + h * DK;
#pragma unroll
    for (int kf = 0; kf < 8; kf++)
        qf[kf] = *(const short8*)(qbase + kf * 32 + quad * 8);

    floatx4 o_acc[16];
#pragma unroll
    for (int i = 0; i < 16; i++) o_acc[i] = (floatx4){0.f, 0.f, 0.f, 0.f};
    float m_i[4] = {-3e38f, -3e38f, -3e38f, -3e38f};
    float l_i[4] = {0.f, 0.f, 0.f, 0.f};

    int srow = tid >> 5;          // staging: 0..7
    int sc16 = tid & 31;
    unsigned short* pw = &Pp[wid * 16 * 72];

    for (int kt = 0; kt < 16; kt++) {
        int k0 = kt * 64;
        __syncthreads();
        // stage K-tile [64 keys][256 dims] -> Ks (pitch 264)
        {
            const unsigned short* kb = Kg + ((size_t)(b * L_ + k0 + srow)) * 1024 + h * DK + sc16 * 8;
            unsigned short* kd = &Ks[srow * 264 + sc16 * 8];
#pragma unroll
            for (int rd = 0; rd < 8; rd++)
                *(short8*)(kd + rd * 8 * 264) = *(const short8*)(kb + (size_t)rd * 8 * 1024);
        }
        __syncthreads();

        // S = Q K^T  (4 nt frags of 16 keys each)
        floatx4 sacc[4];
#pragma unroll
        for (int nt = 0; nt < 4; nt++) sacc[nt] = (floatx4){0.f, 0.f, 0.f, 0.f};
#pragma unroll
        for (int kf = 0; kf < 8; kf++) {
#pragma unroll
            for (int nt = 0; nt < 4; nt++) {
                short8 kfr = *(const short8*)&Ks[(nt * 16 + lr) * 264 + kf * 32 + quad * 8];
                sacc[nt] = __builtin_amdgcn_mfma_f32_16x16x32_bf16(qf[kf], kfr, sacc[nt], 0, 0, 0);
            }
        }

        // online softmax update (rows quad*4+i, cols nt*16+lr)
        float p_[4][4];
        float al[4];
#pragma unroll
        for (int i = 0; i < 4; i++) {
            float tm = sacc[0][i];
            tm = fmaxf(tm, sacc[1][i]);
            tm = fmaxf(tm, sacc[2][i]);
            tm = fmaxf(tm, sacc[3][i]);
            tm *= scale;
            tm = fmaxf(tm, __shfl_xor(tm, 1));
            tm = fmaxf(tm, __shfl_xor(tm, 2));
            tm = fmaxf(tm, __shfl_xor(tm, 4));
            tm = fmaxf(tm, __shfl_xor(tm, 8));
            float mn = fmaxf(m_i[i], tm);
            al[i] = __expf(m_i[i] - mn);
            m_i[i] = mn;
            float ts = 0.f;
#pragma unroll
            for (int nt = 0; nt < 4; nt++) {
                float pv = __expf(sacc[nt][i] * scale - mn);
                p_[nt][i] = pv;
                ts += pv;
            }
            ts += __shfl_xor(ts, 1);
            ts += __shfl_xor(ts, 2);
            ts += __shfl_xor(ts, 4);
            ts += __shfl_xor(ts, 8);
            l_i[i] = al[i] * l_i[i] + ts;
        }

        // write P (bf16) to per-wave LDS region
#pragma unroll
        for (int nt = 0; nt < 4; nt++)
#pragma unroll
            for (int i = 0; i < 4; i++)
                pw[(quad * 4 + i) * 72 + nt * 16 + lr] = f2bf(p_[nt][i]);

        // rescale O
#pragma unroll
        for (int ntd = 0; ntd < 16; ntd++) {
            floatx4 t = o_acc[ntd];
            t[0] *= al[0]; t[1] *= al[1]; t[2] *= al[2]; t[3] *= al[3];
            o_acc[ntd] = t;
        }

        // O += P @ V   (V^T frags from global VT)
        const unsigned short* vb = VT + ((size_t)bh * DK + lr) * 1024 + k0 + quad * 8;
#pragma unroll
        for (int ko = 0; ko < 2; ko++) {
            short8 pf = *(const short8*)&pw[lr * 72 + ko * 32 + quad * 8];
#pragma unroll
            for (int ntd = 0; ntd < 16; ntd++) {
                short8 vf = *(const short8*)(vb + (size_t)ntd * 16 * 1024 + ko * 32);
                o_acc[ntd] = __builtin_amdgcn_mfma_f32_16x16x32_bf16(pf, vf, o_acc[ntd], 0, 0, 0);
            }
        }
    }

    // epilogue: O /= l, store bf16
    float inv[4];
#pragma unroll
    for (int i = 0; i < 4; i++) inv[i] = 1.0f / l_i[i];
    unsigned short* ob = O + ((size_t)(b * L_ + q0 + wid * 16 + quad * 4)) * 1024 + h * DK + lr;
#pragma unroll
    for (int ntd = 0; ntd < 16; ntd++)
#pragma unroll
        for (int i = 0; i < 4; i++)
            ob[(size_t)i * 1024 + ntd * 16] = f2bf(o_acc[ntd][i] * inv[i]);
}

// ---------------------------------------------------------------------------
// Depthwise causal conv1d + bias + SiLU; writes fp32 u and bf16 u
// ---------------------------------------------------------------------------
__global__ __launch_bounds__(256) void conv_silu_kernel(
    const float* __restrict__ xx, const float* __restrict__ cw,
    const float* __restrict__ cb, float* __restrict__ u,
    unsigned short* __restrict__ ub)
{
    int idx = blockIdx.x * 256 + threadIdx.x;
    int d = idx & (DI - 1);
    int l = (idx >> 10) & (L_ - 1);
    int b = idx >> 20;
    const float* xb = xx + (size_t)b * L_ * DI + d;
    float z = cb[d];
#pragma unroll
    for (int j = 0; j < DCV; j++) {
        int t = l - (DCV - 1) + j;
        if (t >= 0) z += xb[(size_t)t * DI] * cw[d * DCV + j];
    }
    float v = z / (1.0f + __expf(-z));
    u[idx] = v;
    ub[idx] = f2bf(v);
}

// ---------------------------------------------------------------------------
// Scan phase A: one thread = (b,d,chunk), 16 states in registers.
// ---------------------------------------------------------------------------
__global__ __launch_bounds__(256) void scan_a(
    const float* __restrict__ delta, const float* __restrict__ u,
    const float* __restrict__ xdbl, const float* __restrict__ A_log,
    float* __restrict__ Hc, float* __restrict__ sumdv)
{
    int gid = blockIdx.x * 256 + threadIdx.x;
    int c = gid >> 12;
    int bd = gid & 4095;
    int b = bd >> 10, d = bd & 1023;

    float a[16];
#pragma unroll
    for (int j = 0; j < 4; j++) {
        float4 al = *(const float4*)(A_log + d * 16 + j * 4);
        a[j * 4 + 0] = -__expf(al.x); a[j * 4 + 1] = -__expf(al.y);
        a[j * 4 + 2] = -__expf(al.z); a[j * 4 + 3] = -__expf(al.w);
    }
    float h[16];
#pragma unroll
    for (int n = 0; n < 16; n++) h[n] = 0.f;
    float sd = 0.f;

    int t0 = c * CHL;
    const float* dp = delta + ((size_t)(b * L_) + t0) * DI + d;
    const float* up = u + ((size_t)(b * L_) + t0) * DI + d;
    const float* xp = xdbl + ((size_t)(b * L_) + t0) * 128;

#pragma unroll 4
    for (int t = 0; t < CHL; t++) {
        float dv = dp[t * DI];
        float uv = up[t * DI];
        float duv = dv * uv;
        sd += dv;
        float Bv[16];
#pragma unroll
        for (int j = 0; j < 4; j++) {
            float4 bq = *(const float4*)(xp + t * 128 + 64 + j * 4);
            Bv[j * 4 + 0] = bq.x; Bv[j * 4 + 1] = bq.y;
            Bv[j * 4 + 2] = bq.z; Bv[j * 4 + 3] = bq.w;
        }
#pragma unroll
        for (int n = 0; n < 16; n++)
            h[n] = __expf(dv * a[n]) * h[n] + duv * Bv[n];
    }

    float* hp = Hc + ((size_t)c * 4096 + bd) * 16;
#pragma unroll
    for (int j = 0; j < 4; j++)
        *(float4*)(hp + j * 4) = make_float4(h[j * 4], h[j * 4 + 1], h[j * 4 + 2], h[j * 4 + 3]);
    sumdv[c * 4096 + bd] = sd;
}

// ---------------------------------------------------------------------------
// Scan phase B: in-place combine — Hc[c][bd][*] becomes chunk START state
// ---------------------------------------------------------------------------
__global__ __launch_bounds__(256) void scan_b(
    float* __restrict__ Hc, const float* __restrict__ sumdv,
    const float* __restrict__ A_log)
{
    int bd = blockIdx.x * 256 + threadIdx.x;
    int d = bd & 1023;

    float a[16];
#pragma unroll
    for (int j = 0; j < 4; j++) {
        float4 al = *(const float4*)(A_log + d * 16 + j * 4);
        a[j * 4 + 0] = -__expf(al.x); a[j * 4 + 1] = -__expf(al.y);
        a[j * 4 + 2] = -__expf(al.z); a[j * 4 + 3] = -__expf(al.w);
    }
    float H[16];
#pragma unroll
    for (int n = 0; n < 16; n++) H[n] = 0.f;

    for (int c = 0; c < NCH; c++) {
        float* hp = Hc + ((size_t)c * 4096 + bd) * 16;
        float sdv = sumdv[c * 4096 + bd];
        float hc[16];
#pragma unroll
        for (int j = 0; j < 4; j++) {
            float4 q = *(const float4*)(hp + j * 4);
            hc[j * 4 + 0] = q.x; hc[j * 4 + 1] = q.y; hc[j * 4 + 2] = q.z; hc[j * 4 + 3] = q.w;
        }
#pragma unroll
        for (int j = 0; j < 4; j++)
            *(float4*)(hp + j * 4) = make_float4(H[j * 4], H[j * 4 + 1], H[j * 4 + 2], H[j * 4 + 3]);
#pragma unroll
        for (int n = 0; n < 16; n++)
            H[n] = __expf(a[n] * sdv) * H[n] + hc[n];
    }
}

// ---------------------------------------------------------------------------
// Scan phase C: re-run chunk from start state, emit y (bf16)
// ---------------------------------------------------------------------------
__global__ __launch_bounds__(256) void scan_c(
    const float* __restrict__ delta, const float* __restrict__ u,
    const float* __restrict__ xdbl, const float* __restrict__ A_log,
    const float* __restrict__ Dv, const float* __restrict__ Hstart,
    unsigned short* __restrict__ y)
{
    int gid = blockIdx.x * 256 + threadIdx.x;
    int c = gid >> 12;
    int bd = gid & 4095;
    int b = bd >> 10, d = bd & 1023;

    float a[16];
#pragma unroll
    for (int j = 0; j < 4; j++) {
        float4 al = *(const float4*)(A_log + d * 16 + j * 4);
        a[j * 4 + 0] = -__expf(al.x); a[j * 4 + 1] = -__expf(al.y);
        a[j * 4 + 2] = -__expf(al.z); a[j * 4 + 3] = -__expf(al.w);
    }
    float h[16];
    const float* hp = Hstart + ((size_t)c * 4096 + bd) * 16;
#pragma unroll
    for (int j = 0; j < 4; j++) {
        float4 q = *(const float4*)(hp + j * 4);
        h[j * 4 + 0] = q.x; h[j * 4 + 1] = q.y; h[j * 4 + 2] = q.z; h[j * 4 + 3] = q.w;
    }
    float Dd = Dv[d];

    int t0 = c * CHL;
    const float* dp = delta + ((size_t)(b * L_) + t0) * DI + d;
    const float* up = u + ((size_t)(b * L_) + t0) * DI + d;
    const float* xp = xdbl + ((size_t)(b * L_) + t0) * 128;
    unsigned short* yp = y + ((size_t)(b * L_) + t0) * DI + d;

#pragma unroll 4
    for (int t = 0; t < CHL; t++) {
        float dv = dp[t * DI];
        float uv = up[t * DI];
        float duv = dv * uv;
        float Bv[16], Cv[16];
#pragma unroll
        for (int j = 0; j < 4; j++) {
            float4 bq = *(const float4*)(xp + t * 128 + 64 + j * 4);
            Bv[j * 4 + 0] = bq.x; Bv[j * 4 + 1] = bq.y;
            Bv[j * 4 + 2] = bq.z; Bv[j * 4 + 3] = bq.w;
            float4 cq = *(const float4*)(xp + t * 128 + 80 + j * 4);
            Cv[j * 4 + 0] = cq.x; Cv[j * 4 + 1] = cq.y;
            Cv[j * 4 + 2] = cq.z; Cv[j * 4 + 3] = cq.w;
        }
        float ys = 0.f;
#pragma unroll
        for (int n = 0; n < 16; n++) {
            h[n] = __expf(dv * a[n]) * h[n] + duv * Bv[n];
            ys += h[n] * Cv[n];
        }
        yp[t * DI] = f2bf(ys + uv * Dd);
    }
}

// ---------------------------------------------------------------------------
// V [4096][1024] -> VT [bh][256][1024] (bf16 tiled transpose)
// ---------------------------------------------------------------------------
__global__ __launch_bounds__(256) void transpose_v(
    const unsigned short* __restrict__ V, unsigned short* __restrict__ VT)
{
    __shared__ unsigned short tl[32][36];
    int bh = blockIdx.z;
    int b = bh >> 2, h = bh & 3;
    int l0 = blockIdx.x * 32, d0 = blockIdx.y * 32;
    int tid = threadIdx.x;
    int r = tid >> 3, c4 = (tid & 7) * 4;

    const unsigned short* src = V + ((size_t)(b * L_ + l0 + r)) * 1024 + h * DK + d0 + c4;
    ushort4 v = *(const ushort4*)src;
    tl[r][c4 + 0] = v.x; tl[r][c4 + 1] = v.y; tl[r][c4 + 2] = v.z; tl[r][c4 + 3] = v.w;
    __syncthreads();

    unsigned short* dst = VT + ((size_t)bh * DK + d0 + r) * L_ + l0 + c4;
    ushort4 o;
    o.x = tl[c4 + 0][r]; o.y = tl[c4 + 1][r]; o.z = tl[c4 + 2][r]; o.w = tl[c4 + 3][r];
    *(ushort4*)dst = o;
}

// ---------------------------------------------------------------------------
extern "C" void kernel_launch(void* const* d_in, const int* in_sizes, int n_in,
                              void* d_out, int out_size, void* d_ws, size_t ws_size,
                              hipStream_t stream)
{
    const float* x         = (const float*)d_in[0];
    const float* xx        = (const float*)d_in[1];
    const float* in_proj_w = (const float*)d_in[2];
    const float* conv_w    = (const float*)d_in[3];
    const float* conv_b    = (const float*)d_in[4];
    const float* x_proj_w  = (const float*)d_in[5];
    const float* dt_proj_w = (const float*)d_in[6];
    const float* dt_proj_b = (const float*)d_in[7];
    const float* A_log     = (const float*)d_in[8];
    const float* Dvec      = (const float*)d_in[9];
    const float* wq        = (const float*)d_in[10];
    const float* bq        = (const float*)d_in[11];
    const float* wk        = (const float*)d_in[12];
    const float* bk        = (const float*)d_in[13];
    const float* wv        = (const float*)d_in[14];
    const float* bv        = (const float*)d_in[15];
    const float* wo        = (const float*)d_in[16];
    const float* bo        = (const float*)d_in[17];
    float* out = (float*)d_out;

    char* w = (char*)d_ws;
    const size_t MB = 1024 * 1024, KB = 1024;
    float*          u_f    = (float*)(w + 0);                // 16 MB
    float*          delta  = (float*)(w + 16 * MB);          // 16 MB
    unsigned short* x_bf   = (unsigned short*)(w + 32 * MB); // 8 MB -> Q_bf
    unsigned short* Q_bf   = x_bf;
    unsigned short* q_bf   = (unsigned short*)(w + 40 * MB); // 8 MB -> VT
    unsigned short* VT     = q_bf;
    unsigned short* y_bf   = (unsigned short*)(w + 48 * MB); // 8 MB -> AO
    unsigned short* AO     = y_bf;
    unsigned short* K_bf   = (unsigned short*)(w + 56 * MB); // 8 MB
    unsigned short* V_bf   = (unsigned short*)(w + 64 * MB); // 8 MB
    unsigned short* u_bf   = (unsigned short*)(w + 72 * MB); // 8 MB -> Hc
    float*          Hc     = (float*)(w + 72 * MB);
    float*          xdbl   = (float*)(w + 80 * MB);          // 2 MB
    unsigned short* xdblb  = (unsigned short*)(w + 82 * MB); // 1 MB
    unsigned short* w_in   = (unsigned short*)(w + 83 * MB); // 2 MB
    unsigned short* w_q    = (unsigned short*)(w + 85 * MB); // 2 MB
    unsigned short* w_k    = (unsigned short*)(w + 87 * MB); // 2 MB
    unsigned short* w_v    = (unsigned short*)(w + 89 * MB); // 2 MB
    unsigned short* w_o    = (unsigned short*)(w + 91 * MB); // 2 MB
    unsigned short* w_xp   = (unsigned short*)(w + 93 * MB);            // 256 KB
    unsigned short* w_dt   = (unsigned short*)(w + 93 * MB + 256 * KB); // 128 KB
    float*          sumdv  = (float*)(w + 93 * MB + 384 * KB);          // 512 KB

    dim3 blk(256);

    // 1. fused casts
    CastArgs ca;
    ca.s[0] = x;         ca.d[0] = x_bf;  ca.n[0] = 4194304; ca.ns[0] = 4194304;
    ca.s[1] = in_proj_w; ca.d[1] = w_in;  ca.n[1] = 1048576; ca.ns[1] = 1048576;
    ca.s[2] = wq;        ca.d[2] = w_q;   ca.n[2] = 1048576; ca.ns[2] = 1048576;
    ca.s[3] = wk;        ca.d[3] = w_k;   ca.n[3] = 1048576; ca.ns[3] = 1048576;
    ca.s[4] = wv;        ca.d[4] = w_v;   ca.n[4] = 1048576; ca.ns[4] = 1048576;
    ca.s[5] = wo;        ca.d[5] = w_o;   ca.n[5] = 1048576; ca.ns[5] = 1048576;
    ca.s[6] = x_proj_w;  ca.d[6] = w_xp;  ca.n[6] = 131072;  ca.ns[6] = 98304;
    ca.s[7] = dt_proj_w; ca.d[7] = w_dt;  ca.n[7] = 65536;   ca.ns[7] = 65536;
    cast_multi<<<dim3(4096, 8), blk, 0, stream>>>(ca);

    // 2. conv + silu
    conv_silu_kernel<<<dim3(16384), blk, 0, stream>>>(xx, conv_w, conv_b, u_f, u_bf);

    // 3. in_proj || x_proj
    {
        GArgs ga = {};
        ga.g[0] = (GDesc){x_bf, w_in, nullptr, nullptr, q_bf,
                          1024, 1024, 1024, 1024, 0, 1, 1.0f, 8, 32};
        ga.g[1] = (GDesc){u_bf, w_xp, nullptr, xdbl, xdblb,
                          1024, 1024, 1024, 128, 128, 2, 1.0f, 1, 32};
        gemm_multi<<<dim3(8, 32, 2), blk, 0, stream>>>(ga);
    }
    // 4. dt_proj (softplus)
    {
        GArgs ga = {};
        ga.g[0] = (GDesc){xdblb, w_dt, dt_proj_b, delta, nullptr,
                          64, 128, 64, 1024, 0, 0 | 4, 1.0f, 8, 32};
        gemm_multi<<<dim3(8, 32, 1), blk, 0, stream>>>(ga);
    }
    // 5-7. chunked scan
    scan_a<<<dim3(512), blk, 0, stream>>>(delta, u_f, xdbl, A_log, Hc, sumdv);
    scan_b<<<dim3(16), blk, 0, stream>>>(Hc, sumdv, A_log);
    scan_c<<<dim3(512), blk, 0, stream>>>(delta, u_f, xdbl, A_log, Dvec, Hc, y_bf);

    // 8. Q || K || V projections
    {
        GArgs ga = {};
        ga.g[0] = (GDesc){q_bf, w_q, bq, nullptr, Q_bf, 1024, 1024, 1024, 1024, 0, 1, 1.0f, 8, 32};
        ga.g[1] = (GDesc){y_bf, w_k, bk, nullptr, K_bf, 1024, 1024, 1024, 1024, 0, 1, 1.0f, 8, 32};
        ga.g[2] = (GDesc){y_bf, w_v, bv, nullptr, V_bf, 1024, 1024, 1024, 1024, 0, 1, 1.0f, 8, 32};
        gemm_multi<<<dim3(8, 32, 3), blk, 0, stream>>>(ga);
    }
    // 9. V transpose (VT overwrites q_bf, which was consumed by Q projection)
    transpose_v<<<dim3(32, 8, 16), blk, 0, stream>>>(V_bf, VT);
    // 10. flash attention -> AO (overwrites y_bf, consumed by K/V projections)
    flash_attn<<<dim3(16, 16), blk, 0, stream>>>(Q_bf, K_bf, VT, AO);
    // 11. out = AO @ wo^T + bo (fp32)
    {
        GArgs ga = {};
        ga.g[0] = (GDesc){AO, w_o, bo, out, nullptr, 1024, 1024, 1024, 1024, 0, 0, 1.0f, 8, 32};
        gemm_multi<<<dim3(8, 32, 1), blk, 0, stream>>>(ga);
    }
}

// Round 6
// 469.819 us; speedup vs baseline: 1.0203x; 1.0203x over previous
//
#include <hip/hip_runtime.h>
#include <math.h>

#define B_  4
#define L_  1024
#define DM  1024
#define DI  1024
#define DS  16
#define DR  64
#define DCV 4
#define NH  4
#define DK  256

#define NCH 32         // scan time-chunks
#define CHL (L_ / NCH) // 32 steps per chunk

typedef __attribute__((ext_vector_type(8))) short short8;
typedef __attribute__((ext_vector_type(4))) float floatx4;

static __device__ __forceinline__ unsigned short f2bf(float f) {
    unsigned int u = __float_as_uint(f);
    u += 0x7fffu + ((u >> 16) & 1u);
    return (unsigned short)(u >> 16);
}
static __device__ __forceinline__ float bf2f(unsigned short s) {
    return __uint_as_float(((unsigned int)s) << 16);
}

// ---------------------------------------------------------------------------
// Fused fp32->bf16 casts (8 regions, grid.y selects; pads with zeros past ns)
// ---------------------------------------------------------------------------
struct CastArgs {
    const float* s[8];
    unsigned short* d[8];
    int n[8];
    int ns[8];
};

__global__ __launch_bounds__(256) void cast_multi(CastArgs ca)
{
    int y = blockIdx.y;
    int i = (blockIdx.x * 256 + threadIdx.x) * 4;
    if (i >= ca.n[y]) return;
    const float* s = ca.s[y];
    unsigned short* d = ca.d[y];
    int ns = ca.ns[y];
    ushort4 o;
    if (i + 4 <= ns) {
        float4 v = *(const float4*)(s + i);
        o.x = f2bf(v.x); o.y = f2bf(v.y); o.z = f2bf(v.z); o.w = f2bf(v.w);
    } else {
        float v[4];
#pragma unroll
        for (int j = 0; j < 4; j++) v[j] = (i + j < ns) ? s[i + j] : 0.f;
        o.x = f2bf(v[0]); o.y = f2bf(v[1]); o.z = f2bf(v[2]); o.w = f2bf(v[3]);
    }
    *(ushort4*)(d + i) = o;
}

// ---------------------------------------------------------------------------
// Multi-descriptor bf16 MFMA GEMM: per z, C = act(A @ W^T * scale + bias)
// mode & 3: 0 = fp32 out, 1 = bf16 out, 2 = both. mode & 4: softplus.
// ---------------------------------------------------------------------------
struct GDesc {
    const unsigned short* A;
    const unsigned short* W;
    const float* bias;
    float* Cf;
    unsigned short* Cb;
    int K, lda, ldw, ldc, ldc2;
    int mode;
    float scale;
    int gx, gy;
};
struct GArgs { GDesc g[3]; };

__global__ __launch_bounds__(256) void gemm_multi(GArgs ga)
{
    GDesc g = ga.g[blockIdx.z];
    if ((int)blockIdx.x >= g.gx || (int)blockIdx.y >= g.gy) return;

    __shared__ __align__(16) unsigned short Asm[128 * 32];
    __shared__ __align__(16) unsigned short Bsm[128 * 32];

    int tid = threadIdx.x;
    int wid = tid >> 6;
    int lane = tid & 63;
    int wm = wid & 1, wn = wid >> 1;
    int lr = lane & 15, quad = lane >> 4;

    const unsigned short* Ab = g.A + (size_t)blockIdx.y * 128 * g.lda;
    const unsigned short* Wb = g.W + (size_t)blockIdx.x * 128 * g.ldw;

    int srow = tid >> 2;
    int scol = (tid & 3) * 8;
    const unsigned short* Ap = Ab + (size_t)srow * g.lda + scol;
    const unsigned short* Wp = Wb + (size_t)srow * g.ldw + scol;

    unsigned short* lA0 = &Asm[(wid * 16) * 32];
    unsigned short* lA1 = &Asm[(64 + wid * 16) * 32];
    unsigned short* lB0 = &Bsm[(wid * 16) * 32];
    unsigned short* lB1 = &Bsm[(64 + wid * 16) * 32];

    floatx4 acc[4][4];
#pragma unroll
    for (int i = 0; i < 4; i++)
#pragma unroll
        for (int j = 0; j < 4; j++) acc[i][j] = (floatx4){0.f, 0.f, 0.f, 0.f};

#define GLL(gp, lp) __builtin_amdgcn_global_load_lds( \
        (const __attribute__((address_space(1))) void*)(gp), \
        (__attribute__((address_space(3))) void*)(lp), 16, 0, 0)

    for (int k0 = 0; k0 < g.K; k0 += 32) {
        GLL(Ap, lA0);
        GLL(Ap + (size_t)64 * g.lda, lA1);
        GLL(Wp, lB0);
        GLL(Wp + (size_t)64 * g.ldw, lB1);
        Ap += 32; Wp += 32;
        __syncthreads();

        short8 af[4], bf[4];
#pragma unroll
        for (int mt = 0; mt < 4; mt++)
            af[mt] = *(const short8*)&Asm[(wm * 64 + mt * 16 + lr) * 32 + quad * 8];
#pragma unroll
        for (int nt = 0; nt < 4; nt++)
            bf[nt] = *(const short8*)&Bsm[(wn * 64 + nt * 16 + lr) * 32 + quad * 8];
#pragma unroll
        for (int mt = 0; mt < 4; mt++)
#pragma unroll
            for (int nt = 0; nt < 4; nt++)
                acc[mt][nt] = __builtin_amdgcn_mfma_f32_16x16x32_bf16(
                    af[mt], bf[nt], acc[mt][nt], 0, 0, 0);
        __syncthreads();
    }
#undef GLL

    int bm = blockIdx.y * 128, bn = blockIdx.x * 128;
    int m = g.mode & 3;
#pragma unroll
    for (int mt = 0; mt < 4; mt++) {
#pragma unroll
        for (int nt = 0; nt < 4; nt++) {
            int row0 = bm + wm * 64 + mt * 16 + quad * 4;
            int col = bn + wn * 64 + nt * 16 + lr;
            float bv = g.bias ? g.bias[col] : 0.f;
#pragma unroll
            for (int i = 0; i < 4; i++) {
                float v = acc[mt][nt][i] * g.scale + bv;
                if (g.mode & 4) v = (v > 15.f) ? v : log1pf(__expf(v));
                if (m == 0) {
                    g.Cf[(size_t)(row0 + i) * g.ldc + col] = v;
                } else if (m == 1) {
                    g.Cb[(size_t)(row0 + i) * g.ldc + col] = f2bf(v);
                } else {
                    g.Cf[(size_t)(row0 + i) * g.ldc + col] = v;
                    g.Cb[(size_t)(row0 + i) * g.ldc2 + col] = f2bf(v);
                }
            }
        }
    }
}

// ---------------------------------------------------------------------------
// Flash attention v2.
// Grid: 256 blocks 1D; bh = id & 15 (all blocks of a bh share id%8 -> same
// XCD -> K/VT/Q stay resident in that XCD's L2). 4 waves x 16 q-rows.
// K tile staged via global_load_lds in FRAGMENT order: fragset idx = kf*4+nt
// occupies Ks[idx*512 .. +512) shorts, lane-contiguous -> conflict-free
// ds_read_b128 and zero-VALU staging. V fragments prefetched into registers.
// ---------------------------------------------------------------------------
__global__ __launch_bounds__(256, 1) void flash_attn(
    const unsigned short* __restrict__ Q, const unsigned short* __restrict__ Kg,
    const unsigned short* __restrict__ VT, unsigned short* __restrict__ O)
{
    __shared__ __align__(16) unsigned short Ks[32 * 512];     // 32 KB
    __shared__ __align__(16) unsigned short Pp[4 * 16 * 72];  // 9 KB

    int id = blockIdx.x;
    int bh = id & 15;
    int qt = id >> 4;
    int b = bh >> 2, h = bh & 3;
    int q0 = qt * 64;
    int tid = threadIdx.x;
    int wid = tid >> 6, lane = tid & 63;
    int lr = lane & 15, quad = lane >> 4;
    const float scale = 0.0625f;   // 1/sqrt(256)

    // Q fragments: rows q0 + wid*16 + lr, all 256 dims
    short8 qf[8];
    const unsigned short* qbase = Q + ((size_t)(b * L_ + q0 + wid * 16 + lr)) * 1024 + h * DK;
#pragma unroll
    for (int kf = 0; kf < 8; kf++)
        qf[kf] = *(const short8*)(qbase + kf * 32 + quad * 8);

    floatx4 o_acc[16];
#pragma unroll
    for (int i = 0; i < 16; i++) o_acc[i] = (floatx4){0.f, 0.f, 0.f, 0.f};
    float m_i[4] = {-3e38f, -3e38f, -3e38f, -3e38f};
    float l_i[4] = {0.f, 0.f, 0.f, 0.f};

    unsigned short* pw = &Pp[wid * 16 * 72];

    // stage K-tile at key offset k0: wave wid issues 8 global_load_lds,
    // fragset f = wid*8+j -> nt = f&3, kf = f>>2
    // per-lane addr: row k0 + nt*16 + lr, col h*256 + kf*32 + quad*8
    {
#pragma unroll
        for (int j = 0; j < 8; j++) {
            int f = wid * 8 + j;
            int nt_ = f & 3, kf_ = f >> 2;
            const unsigned short* gp = Kg + ((size_t)(b * L_ + nt_ * 16 + lr)) * 1024
                                       + h * DK + kf_ * 32 + quad * 8;
            __builtin_amdgcn_global_load_lds(
                (const __attribute__((address_space(1))) void*)gp,
                (__attribute__((address_space(3))) void*)(&Ks[(kf_ * 4 + nt_) * 512]),
                16, 0, 0);
        }
    }
    __syncthreads();

    const unsigned short* vbase = VT + ((size_t)bh * DK + lr) * 1024 + quad * 8;

    for (int kt = 0; kt < 16; kt++) {
        int k0 = kt * 64;

        // prefetch V fragments, first half (k0 .. k0+31)
        short8 vf0[16], vf1[16];
#pragma unroll
        for (int ntd = 0; ntd < 16; ntd++)
            vf0[ntd] = *(const short8*)(vbase + (size_t)ntd * 16 * 1024 + k0);

        // S = Q K^T
        floatx4 sacc[4];
#pragma unroll
        for (int nt = 0; nt < 4; nt++) sacc[nt] = (floatx4){0.f, 0.f, 0.f, 0.f};
#pragma unroll
        for (int kf = 0; kf < 8; kf++) {
#pragma unroll
            for (int nt = 0; nt < 4; nt++) {
                short8 kfr = *(const short8*)&Ks[(kf * 4 + nt) * 512 + lane * 8];
                sacc[nt] = __builtin_amdgcn_mfma_f32_16x16x32_bf16(qf[kf], kfr, sacc[nt], 0, 0, 0);
            }
        }

        // prefetch V fragments, second half
#pragma unroll
        for (int ntd = 0; ntd < 16; ntd++)
            vf1[ntd] = *(const short8*)(vbase + (size_t)ntd * 16 * 1024 + k0 + 32);

        // online softmax update (rows quad*4+i, cols nt*16+lr)
        float p_[4][4];
        float al[4];
#pragma unroll
        for (int i = 0; i < 4; i++) {
            float tm = sacc[0][i];
            tm = fmaxf(tm, sacc[1][i]);
            tm = fmaxf(tm, sacc[2][i]);
            tm = fmaxf(tm, sacc[3][i]);
            tm *= scale;
            tm = fmaxf(tm, __shfl_xor(tm, 1));
            tm = fmaxf(tm, __shfl_xor(tm, 2));
            tm = fmaxf(tm, __shfl_xor(tm, 4));
            tm = fmaxf(tm, __shfl_xor(tm, 8));
            float mn = fmaxf(m_i[i], tm);
            al[i] = __expf(m_i[i] - mn);
            m_i[i] = mn;
            float ts = 0.f;
#pragma unroll
            for (int nt = 0; nt < 4; nt++) {
                float pv = __expf(sacc[nt][i] * scale - mn);
                p_[nt][i] = pv;
                ts += pv;
            }
            ts += __shfl_xor(ts, 1);
            ts += __shfl_xor(ts, 2);
            ts += __shfl_xor(ts, 4);
            ts += __shfl_xor(ts, 8);
            l_i[i] = al[i] * l_i[i] + ts;
        }

        // write P (bf16) to per-wave LDS region (C-layout -> A-layout)
#pragma unroll
        for (int nt = 0; nt < 4; nt++)
#pragma unroll
            for (int i = 0; i < 4; i++)
                pw[(quad * 4 + i) * 72 + nt * 16 + lr] = f2bf(p_[nt][i]);

        // rescale O
#pragma unroll
        for (int ntd = 0; ntd < 16; ntd++) {
            floatx4 t = o_acc[ntd];
            t[0] *= al[0]; t[1] *= al[1]; t[2] *= al[2]; t[3] *= al[3];
            o_acc[ntd] = t;
        }

        // O += P @ V (V from prefetched registers)
        short8 pf0 = *(const short8*)&pw[lr * 72 + quad * 8];
        short8 pf1 = *(const short8*)&pw[lr * 72 + 32 + quad * 8];
#pragma unroll
        for (int ntd = 0; ntd < 16; ntd++)
            o_acc[ntd] = __builtin_amdgcn_mfma_f32_16x16x32_bf16(pf0, vf0[ntd], o_acc[ntd], 0, 0, 0);
#pragma unroll
        for (int ntd = 0; ntd < 16; ntd++)
            o_acc[ntd] = __builtin_amdgcn_mfma_f32_16x16x32_bf16(pf1, vf1[ntd], o_acc[ntd], 0, 0, 0);

        __syncthreads();   // all waves done reading Ks
        if (kt < 15) {
            int kn = k0 + 64;
#pragma unroll
            for (int j = 0; j < 8; j++) {
                int f = wid * 8 + j;
                int nt_ = f & 3, kf_ = f >> 2;
                const unsigned short* gp = Kg + ((size_t)(b * L_ + kn + nt_ * 16 + lr)) * 1024
                                           + h * DK + kf_ * 32 + quad * 8;
                __builtin_amdgcn_global_load_lds(
                    (const __attribute__((address_space(1))) void*)gp,
                    (__attribute__((address_space(3))) void*)(&Ks[(kf_ * 4 + nt_) * 512]),
                    16, 0, 0);
            }
        }
        __syncthreads();   // staging complete before next iteration reads
    }

    // epilogue: O /= l, store bf16
    float inv[4];
#pragma unroll
    for (int i = 0; i < 4; i++) inv[i] = 1.0f / l_i[i];
    unsigned short* ob = O + ((size_t)(b * L_ + q0 + wid * 16 + quad * 4)) * 1024 + h * DK + lr;
#pragma unroll
    for (int ntd = 0; ntd < 16; ntd++)
#pragma unroll
        for (int i = 0; i < 4; i++)
            ob[(size_t)i * 1024 + ntd * 16] = f2bf(o_acc[ntd][i] * inv[i]);
}

// ---------------------------------------------------------------------------
// Depthwise causal conv1d + bias + SiLU; writes fp32 u and bf16 u
// ---------------------------------------------------------------------------
__global__ __launch_bounds__(256) void conv_silu_kernel(
    const float* __restrict__ xx, const float* __restrict__ cw,
    const float* __restrict__ cb, float* __restrict__ u,
    unsigned short* __restrict__ ub)
{
    int idx = blockIdx.x * 256 + threadIdx.x;
    int d = idx & (DI - 1);
    int l = (idx >> 10) & (L_ - 1);
    int b = idx >> 20;
    const float* xb = xx + (size_t)b * L_ * DI + d;
    float z = cb[d];
#pragma unroll
    for (int j = 0; j < DCV; j++) {
        int t = l - (DCV - 1) + j;
        if (t >= 0) z += xb[(size_t)t * DI] * cw[d * DCV + j];
    }
    float v = z / (1.0f + __expf(-z));
    u[idx] = v;
    ub[idx] = f2bf(v);
}

// ---------------------------------------------------------------------------
// Scan phase A: one thread = (b,d,chunk), 16 states in registers.
// ---------------------------------------------------------------------------
__global__ __launch_bounds__(256) void scan_a(
    const float* __restrict__ delta, const float* __restrict__ u,
    const float* __restrict__ xdbl, const float* __restrict__ A_log,
    float* __restrict__ Hc, float* __restrict__ sumdv)
{
    int gid = blockIdx.x * 256 + threadIdx.x;
    int c = gid >> 12;
    int bd = gid & 4095;
    int b = bd >> 10, d = bd & 1023;

    float a[16];
#pragma unroll
    for (int j = 0; j < 4; j++) {
        float4 al = *(const float4*)(A_log + d * 16 + j * 4);
        a[j * 4 + 0] = -__expf(al.x); a[j * 4 + 1] = -__expf(al.y);
        a[j * 4 + 2] = -__expf(al.z); a[j * 4 + 3] = -__expf(al.w);
    }
    float h[16];
#pragma unroll
    for (int n = 0; n < 16; n++) h[n] = 0.f;
    float sd = 0.f;

    int t0 = c * CHL;
    const float* dp = delta + ((size_t)(b * L_) + t0) * DI + d;
    const float* up = u + ((size_t)(b * L_) + t0) * DI + d;
    const float* xp = xdbl + ((size_t)(b * L_) + t0) * 128;

#pragma unroll 4
    for (int t = 0; t < CHL; t++) {
        float dv = dp[t * DI];
        float uv = up[t * DI];
        float duv = dv * uv;
        sd += dv;
        float Bv[16];
#pragma unroll
        for (int j = 0; j < 4; j++) {
            float4 bq = *(const float4*)(xp + t * 128 + 64 + j * 4);
            Bv[j * 4 + 0] = bq.x; Bv[j * 4 + 1] = bq.y;
            Bv[j * 4 + 2] = bq.z; Bv[j * 4 + 3] = bq.w;
        }
#pragma unroll
        for (int n = 0; n < 16; n++)
            h[n] = __expf(dv * a[n]) * h[n] + duv * Bv[n];
    }

    float* hp = Hc + ((size_t)c * 4096 + bd) * 16;
#pragma unroll
    for (int j = 0; j < 4; j++)
        *(float4*)(hp + j * 4) = make_float4(h[j * 4], h[j * 4 + 1], h[j * 4 + 2], h[j * 4 + 3]);
    sumdv[c * 4096 + bd] = sd;
}

// ---------------------------------------------------------------------------
// Scan phase B: in-place combine — Hc[c][bd][*] becomes chunk START state
// ---------------------------------------------------------------------------
__global__ __launch_bounds__(256) void scan_b(
    float* __restrict__ Hc, const float* __restrict__ sumdv,
    const float* __restrict__ A_log)
{
    int bd = blockIdx.x * 256 + threadIdx.x;
    int d = bd & 1023;

    float a[16];
#pragma unroll
    for (int j = 0; j < 4; j++) {
        float4 al = *(const float4*)(A_log + d * 16 + j * 4);
        a[j * 4 + 0] = -__expf(al.x); a[j * 4 + 1] = -__expf(al.y);
        a[j * 4 + 2] = -__expf(al.z); a[j * 4 + 3] = -__expf(al.w);
    }
    float H[16];
#pragma unroll
    for (int n = 0; n < 16; n++) H[n] = 0.f;

    for (int c = 0; c < NCH; c++) {
        float* hp = Hc + ((size_t)c * 4096 + bd) * 16;
        float sdv = sumdv[c * 4096 + bd];
        float hc[16];
#pragma unroll
        for (int j = 0; j < 4; j++) {
            float4 q = *(const float4*)(hp + j * 4);
            hc[j * 4 + 0] = q.x; hc[j * 4 + 1] = q.y; hc[j * 4 + 2] = q.z; hc[j * 4 + 3] = q.w;
        }
#pragma unroll
        for (int j = 0; j < 4; j++)
            *(float4*)(hp + j * 4) = make_float4(H[j * 4], H[j * 4 + 1], H[j * 4 + 2], H[j * 4 + 3]);
#pragma unroll
        for (int n = 0; n < 16; n++)
            H[n] = __expf(a[n] * sdv) * H[n] + hc[n];
    }
}

// ---------------------------------------------------------------------------
// Scan phase C: re-run chunk from start state, emit y (bf16)
// ---------------------------------------------------------------------------
__global__ __launch_bounds__(256) void scan_c(
    const float* __restrict__ delta, const float* __restrict__ u,
    const float* __restrict__ xdbl, const float* __restrict__ A_log,
    const float* __restrict__ Dv, const float* __restrict__ Hstart,
    unsigned short* __restrict__ y)
{
    int gid = blockIdx.x * 256 + threadIdx.x;
    int c = gid >> 12;
    int bd = gid & 4095;
    int b = bd >> 10, d = bd & 1023;

    float a[16];
#pragma unroll
    for (int j = 0; j < 4; j++) {
        float4 al = *(const float4*)(A_log + d * 16 + j * 4);
        a[j * 4 + 0] = -__expf(al.x); a[j * 4 + 1] = -__expf(al.y);
        a[j * 4 + 2] = -__expf(al.z); a[j * 4 + 3] = -__expf(al.w);
    }
    float h[16];
    const float* hp = Hstart + ((size_t)c * 4096 + bd) * 16;
#pragma unroll
    for (int j = 0; j < 4; j++) {
        float4 q = *(const float4*)(hp + j * 4);
        h[j * 4 + 0] = q.x; h[j * 4 + 1] = q.y; h[j * 4 + 2] = q.z; h[j * 4 + 3] = q.w;
    }
    float Dd = Dv[d];

    int t0 = c * CHL;
    const float* dp = delta + ((size_t)(b * L_) + t0) * DI + d;
    const float* up = u + ((size_t)(b * L_) + t0) * DI + d;
    const float* xp = xdbl + ((size_t)(b * L_) + t0) * 128;
    unsigned short* yp = y + ((size_t)(b * L_) + t0) * DI + d;

#pragma unroll 4
    for (int t = 0; t < CHL; t++) {
        float dv = dp[t * DI];
        float uv = up[t * DI];
        float duv = dv * uv;
        float Bv[16], Cv[16];
#pragma unroll
        for (int j = 0; j < 4; j++) {
            float4 bq = *(const float4*)(xp + t * 128 + 64 + j * 4);
            Bv[j * 4 + 0] = bq.x; Bv[j * 4 + 1] = bq.y;
            Bv[j * 4 + 2] = bq.z; Bv[j * 4 + 3] = bq.w;
            float4 cq = *(const float4*)(xp + t * 128 + 80 + j * 4);
            Cv[j * 4 + 0] = cq.x; Cv[j * 4 + 1] = cq.y;
            Cv[j * 4 + 2] = cq.z; Cv[j * 4 + 3] = cq.w;
        }
        float ys = 0.f;
#pragma unroll
        for (int n = 0; n < 16; n++) {
            h[n] = __expf(dv * a[n]) * h[n] + duv * Bv[n];
            ys += h[n] * Cv[n];
        }
        yp[t * DI] = f2bf(ys + uv * Dd);
    }
}

// ---------------------------------------------------------------------------
// V [4096][1024] -> VT [bh][256][1024] (bf16 tiled transpose)
// ---------------------------------------------------------------------------
__global__ __launch_bounds__(256) void transpose_v(
    const unsigned short* __restrict__ V, unsigned short* __restrict__ VT)
{
    __shared__ unsigned short tl[32][36];
    int bh = blockIdx.z;
    int b = bh >> 2, h = bh & 3;
    int l0 = blockIdx.x * 32, d0 = blockIdx.y * 32;
    int tid = threadIdx.x;
    int r = tid >> 3, c4 = (tid & 7) * 4;

    const unsigned short* src = V + ((size_t)(b * L_ + l0 + r)) * 1024 + h * DK + d0 + c4;
    ushort4 v = *(const ushort4*)src;
    tl[r][c4 + 0] = v.x; tl[r][c4 + 1] = v.y; tl[r][c4 + 2] = v.z; tl[r][c4 + 3] = v.w;
    __syncthreads();

    unsigned short* dst = VT + ((size_t)bh * DK + d0 + r) * L_ + l0 + c4;
    ushort4 o;
    o.x = tl[c4 + 0][r]; o.y = tl[c4 + 1][r]; o.z = tl[c4 + 2][r]; o.w = tl[c4 + 3][r];
    *(ushort4*)dst = o;
}

// ---------------------------------------------------------------------------
extern "C" void kernel_launch(void* const* d_in, const int* in_sizes, int n_in,
                              void* d_out, int out_size, void* d_ws, size_t ws_size,
                              hipStream_t stream)
{
    const float* x         = (const float*)d_in[0];
    const float* xx        = (const float*)d_in[1];
    const float* in_proj_w = (const float*)d_in[2];
    const float* conv_w    = (const float*)d_in[3];
    const float* conv_b    = (const float*)d_in[4];
    const float* x_proj_w  = (const float*)d_in[5];
    const float* dt_proj_w = (const float*)d_in[6];
    const float* dt_proj_b = (const float*)d_in[7];
    const float* A_log     = (const float*)d_in[8];
    const float* Dvec      = (const float*)d_in[9];
    const float* wq        = (const float*)d_in[10];
    const float* bq        = (const float*)d_in[11];
    const float* wk        = (const float*)d_in[12];
    const float* bk        = (const float*)d_in[13];
    const float* wv        = (const float*)d_in[14];
    const float* bv        = (const float*)d_in[15];
    const float* wo        = (const float*)d_in[16];
    const float* bo        = (const float*)d_in[17];
    float* out = (float*)d_out;

    char* w = (char*)d_ws;
    const size_t MB = 1024 * 1024, KB = 1024;
    float*          u_f    = (float*)(w + 0);                // 16 MB
    float*          delta  = (float*)(w + 16 * MB);          // 16 MB
    unsigned short* x_bf   = (unsigned short*)(w + 32 * MB); // 8 MB -> Q_bf
    unsigned short* Q_bf   = x_bf;
    unsigned short* q_bf   = (unsigned short*)(w + 40 * MB); // 8 MB -> VT
    unsigned short* VT     = q_bf;
    unsigned short* y_bf   = (unsigned short*)(w + 48 * MB); // 8 MB -> AO
    unsigned short* AO     = y_bf;
    unsigned short* K_bf   = (unsigned short*)(w + 56 * MB); // 8 MB
    unsigned short* V_bf   = (unsigned short*)(w + 64 * MB); // 8 MB
    unsigned short* u_bf   = (unsigned short*)(w + 72 * MB); // 8 MB -> Hc
    float*          Hc     = (float*)(w + 72 * MB);
    float*          xdbl   = (float*)(w + 80 * MB);          // 2 MB
    unsigned short* xdblb  = (unsigned short*)(w + 82 * MB); // 1 MB
    unsigned short* w_in   = (unsigned short*)(w + 83 * MB); // 2 MB
    unsigned short* w_q    = (unsigned short*)(w + 85 * MB); // 2 MB
    unsigned short* w_k    = (unsigned short*)(w + 87 * MB); // 2 MB
    unsigned short* w_v    = (unsigned short*)(w + 89 * MB); // 2 MB
    unsigned short* w_o    = (unsigned short*)(w + 91 * MB); // 2 MB
    unsigned short* w_xp   = (unsigned short*)(w + 93 * MB);            // 256 KB
    unsigned short* w_dt   = (unsigned short*)(w + 93 * MB + 256 * KB); // 128 KB
    float*          sumdv  = (float*)(w + 93 * MB + 384 * KB);          // 512 KB

    dim3 blk(256);

    // 1. fused casts
    CastArgs ca;
    ca.s[0] = x;         ca.d[0] = x_bf;  ca.n[0] = 4194304; ca.ns[0] = 4194304;
    ca.s[1] = in_proj_w; ca.d[1] = w_in;  ca.n[1] = 1048576; ca.ns[1] = 1048576;
    ca.s[2] = wq;        ca.d[2] = w_q;   ca.n[2] = 1048576; ca.ns[2] = 1048576;
    ca.s[3] = wk;        ca.d[3] = w_k;   ca.n[3] = 1048576; ca.ns[3] = 1048576;
    ca.s[4] = wv;        ca.d[4] = w_v;   ca.n[4] = 1048576; ca.ns[4] = 1048576;
    ca.s[5] = wo;        ca.d[5] = w_o;   ca.n[5] = 1048576; ca.ns[5] = 1048576;
    ca.s[6] = x_proj_w;  ca.d[6] = w_xp;  ca.n[6] = 131072;  ca.ns[6] = 98304;
    ca.s[7] = dt_proj_w; ca.d[7] = w_dt;  ca.n[7] = 65536;   ca.ns[7] = 65536;
    cast_multi<<<dim3(4096, 8), blk, 0, stream>>>(ca);

    // 2. conv + silu
    conv_silu_kernel<<<dim3(16384), blk, 0, stream>>>(xx, conv_w, conv_b, u_f, u_bf);

    // 3. in_proj || x_proj
    {
        GArgs ga = {};
        ga.g[0] = (GDesc){x_bf, w_in, nullptr, nullptr, q_bf,
                          1024, 1024, 1024, 1024, 0, 1, 1.0f, 8, 32};
        ga.g[1] = (GDesc){u_bf, w_xp, nullptr, xdbl, xdblb,
                          1024, 1024, 1024, 128, 128, 2, 1.0f, 1, 32};
        gemm_multi<<<dim3(8, 32, 2), blk, 0, stream>>>(ga);
    }
    // 4. dt_proj (softplus)
    {
        GArgs ga = {};
        ga.g[0] = (GDesc){xdblb, w_dt, dt_proj_b, delta, nullptr,
                          64, 128, 64, 1024, 0, 0 | 4, 1.0f, 8, 32};
        gemm_multi<<<dim3(8, 32, 1), blk, 0, stream>>>(ga);
    }
    // 5-7. chunked scan
    scan_a<<<dim3(512), blk, 0, stream>>>(delta, u_f, xdbl, A_log, Hc, sumdv);
    scan_b<<<dim3(16), blk, 0, stream>>>(Hc, sumdv, A_log);
    scan_c<<<dim3(512), blk, 0, stream>>>(delta, u_f, xdbl, A_log, Dvec, Hc, y_bf);

    // 8. Q || K || V projections
    {
        GArgs ga = {};
        ga.g[0] = (GDesc){q_bf, w_q, bq, nullptr, Q_bf, 1024, 1024, 1024, 1024, 0, 1, 1.0f, 8, 32};
        ga.g[1] = (GDesc){y_bf, w_k, bk, nullptr, K_bf, 1024, 1024, 1024, 1024, 0, 1, 1.0f, 8, 32};
        ga.g[2] = (GDesc){y_bf, w_v, bv, nullptr, V_bf, 1024, 1024, 1024, 1024, 0, 1, 1.0f, 8, 32};
        gemm_multi<<<dim3(8, 32, 3), blk, 0, stream>>>(ga);
    }
    // 9. V transpose (VT overwrites q_bf, consumed by Q projection)
    transpose_v<<<dim3(32, 8, 16), blk, 0, stream>>>(V_bf, VT);
    // 10. flash attention -> AO (1D grid, XCD-swizzled)
    flash_attn<<<dim3(256), blk, 0, stream>>>(Q_bf, K_bf, VT, AO);
    // 11. out = AO @ wo^T + bo (fp32)
    {
        GArgs ga = {};
        ga.g[0] = (GDesc){AO, w_o, bo, out, nullptr, 1024, 1024, 1024, 1024, 0, 0, 1.0f, 8, 32};
        gemm_multi<<<dim3(8, 32, 1), blk, 0, stream>>>(ga);
    }
}